// Round 1
// baseline (266.254 us; speedup 1.0000x reference)
//
#include <hip/hip_runtime.h>
#include <hip/hip_bf16.h>

// ---------------------------------------------------------------------------
// MeshEstimator (SMPL-like) forward.
// B=256 batches, R=6890 verts, 24 joints, 207 pose-feature dims.
// Inputs (fp32): x[256,88], gender[256,2] one-hot, v_template[2,R,3],
//   shapedirs[2,10,R,3], J_regressor[2,R,24], posedirs[2,R,3,207], weights[2,R,24]
// Outputs (fp32, concatenated): betas[256,10], pose[256,72], root_shift[256,3],
//   root_angles[256,6], verts[256,R,3], verts_red[256,10,3], new_J[256,24,3],
//   verts_offset[256,10,3]
// ---------------------------------------------------------------------------

#define NB 256
#define NR 6890
#define NJ 24
#define BT 32   // batches per vertex-kernel block

// ---- output offsets (floats) ----
#define OFF_BETAS 0
#define OFF_POSE  2560
#define OFF_RSH   20992
#define OFF_RA    21760
#define OFF_VERTS 23296
#define OFF_VRED  5314816
#define OFF_NEWJ  5322496
#define OFF_VOFF  5340928

// ---- workspace offsets (floats) ----
#define WS_RS    0         // Rs: 256*24*9 = 55296
#define WS_PF    55296     // pose_feat: 256*207 = 52992
#define WS_BETA  108288    // 2560
#define WS_RSH   110848    // 768
#define WS_GI    111616    // 256 ints
#define WS_JT    111872    // 2*24*3 = 144
#define WS_JS    112016    // 2*10*24*3 = 1440
#define WS_A     113456    // 256*24*12 = 73728
#define WS_J0S   187184    // 768
#define WS_ORD   187952    // 256 ints
#define WS_CNT   188208    // 2 ints

__constant__ int PAR_c[24] = {0,0,0,0,1,2,3,4,5,6,7,8,9,9,9,12,13,14,16,17,18,19,20,21};
__constant__ int VL_c[10]  = {1325,336,1032,4515,1374,4848,1739,5209,1960,5423};
__constant__ int SY_c[10]  = {3,15,4,5,7,8,18,19,20,21};

// original (pre-doubling) bound values, fp32-cast of the float64 Python values
__constant__ float BLO[72] = {
  -0.5933865286111969f, -6.283185307179586f, -1.215762200416361f,
  -1.5793940868065197f, -0.5881754611f, -0.5323249722f,
  -1.5793940868065197f, -0.5689768556f, -0.6736965222f,
  -1.0471975511965976f, -0.08726646259971647f, -0.08726646259971647f,
  -0.02268926111f, -0.01f, -0.01f,
  -0.02268926111f, -0.01f, -0.01f,
  -1.0471975511965976f, -0.08726646259971647f, -0.08726646259971647f,
  -0.5235987755982988f, -0.5235987755982988f, -0.5235987755982988f,
  -0.5235987755982988f, -0.5235987755982988f, -0.5235987755982988f,
  -1.0471975511965976f, -0.08726646259971647f, -0.08726646259971647f,
  -0.01f, -0.01f, -0.01f, -0.01f, -0.01f, -0.01f,
  -1.0471975511965976f, -0.08726646259971647f, -0.08726646259971647f,
  (float)(-1.551596394/3.0), (float)(-2.455676183/3.0), (float)(-1.570795/3.0),
  (float)(-1.551596394/3.0), (float)(-0.7627082389/3.0), (float)(-2.188641033/3.0),
  -1.0471975511965976f, -0.08726646259971647f, -0.08726646259971647f,
  (float)(-1.551596394*2.0/3.0), (float)(-2.455676183*2.0/3.0), (float)(-1.570795*2.0/3.0),
  (float)(-1.551596394*2.0/3.0), (float)(-0.7627082389*2.0/3.0), (float)(-2.188641033*2.0/3.0),
  -0.01f, -2.570867817f, -0.01f, -0.01f, -0.04799651389f, -0.01f,
  -0.5235987755982988f, -0.5235987755982988f, -0.5235987755982988f,
  -0.5235987755982988f, -0.5235987755982988f, -0.5235987755982988f,
  -0.01f, -0.01f, -0.01f, -0.01f, -0.01f, -0.01f
};
__constant__ float BHI[72] = {
  0.5933865286111969f, 6.283185307179586f, 1.215762200416361f,
  0.3097956806f, 0.5689768556f, 0.6736965222f,
  0.3097956806f, 0.5881754611f, 0.5323249722f,
  1.0471975511965976f, 0.08726646259971647f, 0.08726646259971647f,
  2.441713561f, 0.01f, 0.01f,
  2.441713561f, 0.01f, 0.01f,
  1.0471975511965976f, 0.08726646259971647f, 0.08726646259971647f,
  0.5235987755982988f, 0.5235987755982988f, 0.5235987755982988f,
  0.5235987755982988f, 0.5235987755982988f, 0.5235987755982988f,
  1.0471975511965976f, 0.08726646259971647f, 0.08726646259971647f,
  0.01f, 0.01f, 0.01f, 0.01f, 0.01f, 0.01f,
  1.0471975511965976f, 0.08726646259971647f, 0.08726646259971647f,
  (float)(2.206094311/3.0), (float)(0.7627082389/3.0), (float)(2.188641033/3.0),
  (float)(2.206094311/3.0), (float)(2.455676183/3.0), (float)(1.570795/3.0),
  1.0471975511965976f, 0.08726646259971647f, 0.08726646259971647f,
  (float)(2.206094311*2.0/3.0), (float)(0.7627082389*2.0/3.0), (float)(2.188641033*2.0/3.0),
  (float)(2.206094311*2.0/3.0), (float)(2.455676183*2.0/3.0), (float)(1.570795*2.0/3.0),
  0.01f, 0.04799651389f, 0.01f, 0.01f, 2.570867817f, 0.01f,
  0.5235987755982988f, 0.5235987755982988f, 0.5235987755982988f,
  0.5235987755982988f, 0.5235987755982988f, 0.5235987755982988f,
  0.01f, 0.01f, 0.01f, 0.01f, 0.01f, 0.01f
};

// ---------------------------------------------------------------------------
// K1: per-batch pose clamp, Rodrigues, betas, root outputs, gender index
// ---------------------------------------------------------------------------
__global__ void k1_pose(const float* __restrict__ x, const float* __restrict__ gen,
                        float* __restrict__ out, float* __restrict__ W)
{
  const int b = blockIdx.x, tid = threadIdx.x;
  const float* xb = x + b * 88;
  if (tid < 24) {
    const int j = tid;
    float t[3];
    if (j == 0) {
      t[0] = atan2f(xb[16], xb[13]);
      t[1] = atan2f(xb[17], xb[14]);
      t[2] = atan2f(xb[18], xb[15]);
    } else {
      t[0] = xb[19 + (j - 1) * 3 + 0];
      t[1] = xb[19 + (j - 1) * 3 + 1];
      t[2] = xb[19 + (j - 1) * 3 + 2];
    }
#pragma unroll
    for (int c = 0; c < 3; c++) {
      const int pi = j * 3 + c;
      const float lo = 2.f * BLO[pi], hi = 2.f * BHI[pi];
      const float mean = 0.5f * (lo + hi);
      const float scale = 2.f / fabsf(lo - hi);
      const float v = tanhf((t[c] - mean) * scale) / scale + mean;
      t[c] = v;
      out[OFF_POSE + b * 72 + pi] = v;
    }
    // Rodrigues (matches reference: norm of theta+1e-8, sin/cos of half-angle,
    // quaternion re-normalized)
    const float a0 = t[0] + 1e-8f, a1 = t[1] + 1e-8f, a2 = t[2] + 1e-8f;
    const float ang = sqrtf(a0 * a0 + a1 * a1 + a2 * a2);
    const float half = 0.5f * ang;
    const float sh = sinf(half), ch = cosf(half);
    const float inv = sh / ang;
    float qw = ch, qx = t[0] * inv, qy = t[1] * inv, qz = t[2] * inv;
    const float nn = sqrtf(qw * qw + qx * qx + qy * qy + qz * qz);
    qw /= nn; qx /= nn; qy /= nn; qz /= nn;
    float R[9];
    R[0] = 1.f - 2.f * (qy * qy + qz * qz); R[1] = 2.f * (qx * qy - qw * qz); R[2] = 2.f * (qx * qz + qw * qy);
    R[3] = 2.f * (qx * qy + qw * qz); R[4] = 1.f - 2.f * (qx * qx + qz * qz); R[5] = 2.f * (qy * qz - qw * qx);
    R[6] = 2.f * (qx * qz - qw * qy); R[7] = 2.f * (qy * qz + qw * qx); R[8] = 1.f - 2.f * (qx * qx + qy * qy);
    float* rsw = W + WS_RS + (size_t)(b * 24 + j) * 9;
#pragma unroll
    for (int e = 0; e < 9; e++) rsw[e] = R[e];
    if (j >= 1) {
      float* pfw = W + WS_PF + (size_t)b * 207 + (j - 1) * 9;
#pragma unroll
      for (int e = 0; e < 9; e++)
        pfw[e] = R[e] - ((e == 0 || e == 4 || e == 8) ? 1.f : 0.f);
    }
  } else if (tid < 34) {
    const int k = tid - 24;
    const float v = tanhf(xb[k] / 3.0f) * 3.0f;
    out[OFF_BETAS + b * 10 + k] = v;
    W[WS_BETA + b * 10 + k] = v;
  } else if (tid == 34) {
    const float r0 = xb[10] + (0.6f - 0.286f);
    const float r1 = xb[11] + (1.2f - 0.286f);
    const float r2 = xb[12] + 0.1f;
    out[OFF_RSH + b * 3 + 0] = r0; out[OFF_RSH + b * 3 + 1] = r1; out[OFF_RSH + b * 3 + 2] = r2;
    W[WS_RSH + b * 3 + 0] = r0; W[WS_RSH + b * 3 + 1] = r1; W[WS_RSH + b * 3 + 2] = r2;
#pragma unroll
    for (int k2 = 0; k2 < 6; k2++) out[OFF_RA + b * 6 + k2] = xb[13 + k2];
  } else if (tid == 35) {
    ((int*)(W + WS_GI))[b] = (gen[b * 2 + 1] > gen[b * 2 + 0]) ? 1 : 0;
  }
}

// ---------------------------------------------------------------------------
// K2: per-gender joint regressor decomposition:
//   Jt[g,j,d]   = sum_r v_template[g,r,d] * JR[g,r,j]
//   JS[g,k,j,d] = sum_r shapedirs[g,k,r,d] * JR[g,r,j]
// ---------------------------------------------------------------------------
__global__ void k2_jreg(const float* __restrict__ vtemp, const float* __restrict__ sdirs,
                        const float* __restrict__ jreg, float* __restrict__ W)
{
  const int g = blockIdx.x / 24, j = blockIdx.x % 24;
  const float* vtg = vtemp + (size_t)g * NR * 3;
  const float* sdg = sdirs + (size_t)g * 10 * NR * 3;
  const float* jrg = jreg + (size_t)g * NR * 24;
  float acc[33];
#pragma unroll
  for (int e = 0; e < 33; e++) acc[e] = 0.f;
  for (int r = threadIdx.x; r < NR; r += 256) {
    const float w = jrg[r * 24 + j];
    acc[0] += vtg[r * 3 + 0] * w;
    acc[1] += vtg[r * 3 + 1] * w;
    acc[2] += vtg[r * 3 + 2] * w;
#pragma unroll
    for (int k = 0; k < 10; k++) {
      const float* s = sdg + ((size_t)k * NR + r) * 3;
      acc[3 + k * 3 + 0] += s[0] * w;
      acc[3 + k * 3 + 1] += s[1] * w;
      acc[3 + k * 3 + 2] += s[2] * w;
    }
  }
  __shared__ float red[4][33];
  const int lane = threadIdx.x & 63, wv = threadIdx.x >> 6;
#pragma unroll
  for (int e = 0; e < 33; e++) {
    float v = acc[e];
    v += __shfl_down(v, 32); v += __shfl_down(v, 16); v += __shfl_down(v, 8);
    v += __shfl_down(v, 4);  v += __shfl_down(v, 2);  v += __shfl_down(v, 1);
    if (lane == 0) red[wv][e] = v;
  }
  __syncthreads();
  if (threadIdx.x < 33) {
    const int e = threadIdx.x;
    const float v = red[0][e] + red[1][e] + red[2][e] + red[3][e];
    if (e < 3) W[WS_JT + (g * 24 + j) * 3 + e] = v;
    else {
      const int k = (e - 3) / 3, d = (e - 3) % 3;
      W[WS_JS + ((g * 10 + k) * 24 + j) * 3 + d] = v;
    }
  }
}

// ---------------------------------------------------------------------------
// K_order: compact batches by gender (deterministic, serial — tiny)
// ---------------------------------------------------------------------------
__global__ void k_order(float* __restrict__ W)
{
  if (threadIdx.x != 0 || blockIdx.x != 0) return;
  const int* gi = (const int*)(W + WS_GI);
  int* ord = (int*)(W + WS_ORD);
  int* cnt = (int*)(W + WS_CNT);
  int c0 = 0;
  for (int b = 0; b < NB; b++) if (gi[b] == 0) ord[c0++] = b;
  int c1 = c0;
  for (int b = 0; b < NB; b++) if (gi[b] != 0) ord[c1++] = b;
  cnt[0] = c0; cnt[1] = NB - c0;
}

// ---------------------------------------------------------------------------
// K3: per-batch: J from decomposition, kinematic chain, new_J out, A to ws
// ---------------------------------------------------------------------------
__launch_bounds__(128)
__global__ void k3_chain(float* __restrict__ out, float* __restrict__ W)
{
  const int b = blockIdx.x, tid = threadIdx.x;
  __shared__ float J[72];
  __shared__ float G[24][12];
  __shared__ float j0s[3];
  const int gi = ((const int*)(W + WS_GI))[b];
  if (tid < 72) {
    const int j = tid / 3, d = tid % 3;
    float v = W[WS_JT + (gi * 24 + j) * 3 + d];
    const float* bet = W + WS_BETA + b * 10;
#pragma unroll
    for (int k = 0; k < 10; k++)
      v += bet[k] * W[WS_JS + ((gi * 10 + k) * 24 + j) * 3 + d];
    J[tid] = v;
  }
  __syncthreads();
  const float* Rs = W + WS_RS + (size_t)b * 216;
  if (tid < 12) {
    const int row = tid / 4, col = tid % 4;
    G[0][tid] = (col < 3) ? Rs[row * 3 + col] : J[row * 3 + 0 * 0 + 0 * 0 + 0];  // J[0*3+row]? no:
  }
  // fix: joint-0 translation is J[0] components indexed by row
  if (tid < 12) {
    const int row = tid / 4, col = tid % 4;
    G[0][tid] = (col < 3) ? Rs[row * 3 + col] : J[row];
  }
  __syncthreads();
  for (int i = 1; i < 24; i++) {
    const int p = PAR_c[i];
    if (tid < 12) {
      const int row = tid / 4, col = tid % 4;
      const float* Ri = Rs + i * 9;
      const float g0 = G[p][row * 4 + 0], g1 = G[p][row * 4 + 1], g2 = G[p][row * 4 + 2];
      float v;
      if (col < 3) {
        v = g0 * Ri[col] + g1 * Ri[3 + col] + g2 * Ri[6 + col];
      } else {
        const float t0 = J[i * 3 + 0] - J[p * 3 + 0];
        const float t1 = J[i * 3 + 1] - J[p * 3 + 1];
        const float t2 = J[i * 3 + 2] - J[p * 3 + 2];
        v = g0 * t0 + g1 * t1 + g2 * t2 + G[p][row * 4 + 3];
      }
      G[i][tid] = v;
    }
    __syncthreads();
  }
  if (tid < 3) {
    const float v = W[WS_RSH + b * 3 + tid] - J[tid];
    j0s[tid] = v;
    W[WS_J0S + b * 3 + tid] = v;
  }
  __syncthreads();
  if (tid < 72) {
    const int j = tid / 3, d = tid % 3;
    out[OFF_NEWJ + (size_t)b * 72 + tid] = G[j][d * 4 + 3] + j0s[d];
  }
  for (int e = tid; e < 288; e += 128) {
    const int j = e / 12, rc = e % 12, row = rc / 4, col = rc % 4;
    float v = G[j][rc];
    if (col == 3)
      v -= G[j][row * 4 + 0] * J[j * 3 + 0] + G[j][row * 4 + 1] * J[j * 3 + 1] + G[j][row * 4 + 2] * J[j * 3 + 2];
    W[WS_A + (size_t)b * 288 + e] = v;
  }
}

// ---------------------------------------------------------------------------
// K4: vertices. Block = 256 verts x BT batches (one gender).
// Phase 1: v_posed accumulation (posedirs in regs, pose-feats in LDS).
// Phase 2: LBS skinning (A tile in LDS broadcast, weights in padded LDS).
// ---------------------------------------------------------------------------
struct __align__(16) K4Smem {
  float wls[256 * 25];          // per-thread weights, stride 25 (conflict-free)
  union {
    float A[BT * 288];          // phase-2 A tile
    struct { float pf[BT * 208]; float bet[BT * 10]; } p1;  // phase-1
  } u;
  float j0s[BT * 3];
  int bidx[BT];
  int g, n, start;
};

__launch_bounds__(256, 2)
__global__ void k4_verts(const float* __restrict__ vtemp, const float* __restrict__ sdirs,
                         const float* __restrict__ pdirs, const float* __restrict__ wts,
                         float* __restrict__ out, const float* __restrict__ W)
{
  __shared__ K4Smem sm;
  const int tid = threadIdx.x;
  if (tid == 0) {
    const int* cnt = (const int*)(W + WS_CNT);
    const int B0 = cnt[0], B1 = cnt[1];
    const int T0 = (B0 + BT - 1) / BT;
    const int T1 = (B1 + BT - 1) / BT;
    const int bt = blockIdx.y;
    int g = -1, start = 0, n = 0;
    if (bt < T0) { g = 0; start = bt * BT; n = B0 - start; if (n > BT) n = BT; }
    else if (bt - T0 < T1) { const int b2 = bt - T0; g = 1; start = B0 + b2 * BT; n = NB - start; if (n > BT) n = BT; }
    sm.g = g; sm.n = n; sm.start = start;
  }
  __syncthreads();
  const int g = sm.g, n = sm.n, start = sm.start;
  if (g < 0) return;

  const int* ord = (const int*)(W + WS_ORD);
  if (tid < BT) sm.bidx[tid] = (tid < n) ? ord[start + tid] : 0;
  __syncthreads();

  for (int e = tid; e < BT * 208; e += 256) {
    const int i = e / 208, p = e % 208;
    float v = 0.f;
    if (i < n && p < 207) v = W[WS_PF + (size_t)sm.bidx[i] * 207 + p];
    sm.u.p1.pf[e] = v;
  }
  for (int e = tid; e < BT * 10; e += 256) {
    const int i = e / 10, k = e % 10;
    sm.u.p1.bet[e] = (i < n) ? W[WS_BETA + sm.bidx[i] * 10 + k] : 0.f;
  }
  for (int e = tid; e < BT * 3; e += 256) {
    const int i = e / 3, d = e % 3;
    sm.j0s[e] = (i < n) ? W[WS_J0S + sm.bidx[i] * 3 + d] : 0.f;
  }
  __syncthreads();

  const int r = blockIdx.x * 256 + tid;
  const bool active = (r < NR);
  float acc[BT][3];
  if (active) {
    const float* vt3 = vtemp + ((size_t)g * NR + r) * 3;
    const float vt0 = vt3[0], vt1 = vt3[1], vt2 = vt3[2];
    float sdr[10][3];
#pragma unroll
    for (int k = 0; k < 10; k++) {
      const float* s = sdirs + ((size_t)g * 10 * NR + (size_t)k * NR + r) * 3;
      sdr[k][0] = s[0]; sdr[k][1] = s[1]; sdr[k][2] = s[2];
    }
#pragma unroll
    for (int i = 0; i < BT; i++) {
      float a0 = vt0, a1 = vt1, a2 = vt2;
#pragma unroll
      for (int k = 0; k < 10; k++) {
        const float bk = sm.u.p1.bet[i * 10 + k];
        a0 += bk * sdr[k][0]; a1 += bk * sdr[k][1]; a2 += bk * sdr[k][2];
      }
      acc[i][0] = a0; acc[i][1] = a1; acc[i][2] = a2;
    }
    const float* pdr = pdirs + ((size_t)g * NR + r) * 621;
    for (int p0 = 0; p0 < 200; p0 += 8) {
      float pdv0[8], pdv1[8], pdv2[8];
#pragma unroll
      for (int t = 0; t < 8; t++) {
        pdv0[t] = pdr[p0 + t];
        pdv1[t] = pdr[207 + p0 + t];
        pdv2[t] = pdr[414 + p0 + t];
      }
#pragma unroll
      for (int i = 0; i < BT; i++) {
        const float4 f0 = *(const float4*)&sm.u.p1.pf[i * 208 + p0];
        const float4 f1 = *(const float4*)&sm.u.p1.pf[i * 208 + p0 + 4];
        const float pfv[8] = { f0.x, f0.y, f0.z, f0.w, f1.x, f1.y, f1.z, f1.w };
        float a0 = acc[i][0], a1 = acc[i][1], a2 = acc[i][2];
#pragma unroll
        for (int t = 0; t < 8; t++) {
          a0 += pfv[t] * pdv0[t];
          a1 += pfv[t] * pdv1[t];
          a2 += pfv[t] * pdv2[t];
        }
        acc[i][0] = a0; acc[i][1] = a1; acc[i][2] = a2;
      }
    }
    { // tail p = 200..206
      float pdv0[7], pdv1[7], pdv2[7];
#pragma unroll
      for (int t = 0; t < 7; t++) {
        pdv0[t] = pdr[200 + t];
        pdv1[t] = pdr[407 + t];
        pdv2[t] = pdr[614 + t];
      }
#pragma unroll
      for (int i = 0; i < BT; i++) {
        const float* pfi = &sm.u.p1.pf[i * 208 + 200];
        float a0 = acc[i][0], a1 = acc[i][1], a2 = acc[i][2];
#pragma unroll
        for (int t = 0; t < 7; t++) {
          const float pv = pfi[t];
          a0 += pv * pdv0[t]; a1 += pv * pdv1[t]; a2 += pv * pdv2[t];
        }
        acc[i][0] = a0; acc[i][1] = a1; acc[i][2] = a2;
      }
    }
  } else {
#pragma unroll
    for (int i = 0; i < BT; i++) { acc[i][0] = 0.f; acc[i][1] = 0.f; acc[i][2] = 0.f; }
  }
  __syncthreads();  // done reading pf/bet

  // stage A tile (overwrites pf region)
  for (int e = tid; e < BT * 288; e += 256) {
    const int i = e / 288, rem = e - i * 288;
    sm.u.A[e] = W[WS_A + (size_t)sm.bidx[i] * 288 + rem];
  }
  if (active) {
    const float* wr = wts + ((size_t)g * NR + r) * 24;
#pragma unroll
    for (int j = 0; j < 24; j += 4) {
      const float4 wv = *(const float4*)&wr[j];
      sm.wls[tid * 25 + j + 0] = wv.x;
      sm.wls[tid * 25 + j + 1] = wv.y;
      sm.wls[tid * 25 + j + 2] = wv.z;
      sm.wls[tid * 25 + j + 3] = wv.w;
    }
  }
  __syncthreads();

  if (active) {
#pragma unroll
    for (int i = 0; i < BT; i++) {
      float T[12];
#pragma unroll
      for (int e = 0; e < 12; e++) T[e] = 0.f;
      const float* As = &sm.u.A[i * 288];
      for (int j = 0; j < 24; j++) {
        const float wj = sm.wls[tid * 25 + j];
        const float4 a0 = *(const float4*)(As + j * 12);
        const float4 a1 = *(const float4*)(As + j * 12 + 4);
        const float4 a2 = *(const float4*)(As + j * 12 + 8);
        T[0] += wj * a0.x; T[1] += wj * a0.y; T[2]  += wj * a0.z; T[3]  += wj * a0.w;
        T[4] += wj * a1.x; T[5] += wj * a1.y; T[6]  += wj * a1.z; T[7]  += wj * a1.w;
        T[8] += wj * a2.x; T[9] += wj * a2.y; T[10] += wj * a2.z; T[11] += wj * a2.w;
      }
      if (i < n) {
        const float vx = acc[i][0], vy = acc[i][1], vz = acc[i][2];
        const float o0 = T[0] * vx + T[1] * vy + T[2]  * vz + T[3]  + sm.j0s[i * 3 + 0];
        const float o1 = T[4] * vx + T[5] * vy + T[6]  * vz + T[7]  + sm.j0s[i * 3 + 1];
        const float o2 = T[8] * vx + T[9] * vy + T[10] * vz + T[11] + sm.j0s[i * 3 + 2];
        float* op = out + OFF_VERTS + ((size_t)sm.bidx[i] * NR + r) * 3;
        op[0] = o0; op[1] = o1; op[2] = o2;
      }
    }
  }
}

// ---------------------------------------------------------------------------
// K5: gather verts_red and verts_offset
// ---------------------------------------------------------------------------
__global__ void k5_gather(float* __restrict__ out)
{
  const int idx = blockIdx.x * 256 + threadIdx.x;
  if (idx >= NB * 10 * 3) return;
  const int b = idx / 30, rem = idx % 30, i = rem / 3, d = rem % 3;
  const float v = out[OFF_VERTS + ((size_t)b * NR + VL_c[i]) * 3 + d];
  out[OFF_VRED + idx] = v;
  out[OFF_VOFF + idx] = v - out[OFF_NEWJ + (size_t)b * 72 + SY_c[i] * 3 + d];
}

// ---------------------------------------------------------------------------
extern "C" void kernel_launch(void* const* d_in, const int* in_sizes, int n_in,
                              void* d_out, int out_size, void* d_ws, size_t ws_size,
                              hipStream_t stream)
{
  const float* x   = (const float*)d_in[0];
  const float* gen = (const float*)d_in[1];
  const float* vt  = (const float*)d_in[2];
  const float* sd  = (const float*)d_in[3];
  const float* jr  = (const float*)d_in[4];
  const float* pd  = (const float*)d_in[5];
  const float* wt  = (const float*)d_in[6];
  float* out = (float*)d_out;
  float* W   = (float*)d_ws;

  k1_pose<<<NB, 64, 0, stream>>>(x, gen, out, W);
  k2_jreg<<<48, 256, 0, stream>>>(vt, sd, jr, W);
  k_order<<<1, 64, 0, stream>>>(W);
  k3_chain<<<NB, 128, 0, stream>>>(out, W);
  dim3 g4(27, 9);
  k4_verts<<<g4, 256, 0, stream>>>(vt, sd, pd, wt, out, W);
  k5_gather<<<30, 256, 0, stream>>>(out);
}